// Round 13
// baseline (358.954 us; speedup 1.0000x reference)
//
#include <hip/hip_runtime.h>
#include <hip/hip_bf16.h>

#define NN 50000     // nodes
#define NE 500000    // edges
#define DD 128       // latent size
#define WPAD 140     // Ws row pad (shorts): 280 B = 70 dw == 6 mod 32 -> ~2-way banks
#define EPB 192      // edges per block (4 waves x 48)

typedef float  f32x4 __attribute__((ext_vector_type(4)));
typedef short  s16x8 __attribute__((ext_vector_type(8)));

struct MlpPtrs { const float* W1; const float* b1; const float* W2; const float* b2; int dout; int obase; };
struct MlpArgs { MlpPtrs m[4]; };

__device__ __forceinline__ unsigned short f2bf(float f) {
    unsigned int u = __builtin_bit_cast(unsigned int, f);
    u += 0x7fffu + ((u >> 16) & 1u);           // RNE
    return (unsigned short)(u >> 16);
}

// ---------------------------------------------------------------------------
// Prep: W1T bf16 [m][j][k]  (transposed so B-fragments read 8 contiguous k)
// ---------------------------------------------------------------------------
__global__ void prep_w1t_kernel(const float* __restrict__ W1a, const float* __restrict__ W1b,
                                const float* __restrict__ W1c, const float* __restrict__ W1d,
                                unsigned short* __restrict__ w1t)
{
    int idx = blockIdx.x * blockDim.x + threadIdx.x;   // 4*128*128
    if (idx >= 4 * DD * DD) return;
    int m = idx >> 14, r = idx & 16383;
    int j = r >> 7, k = r & 127;
    const float* W1 = (m == 0) ? W1a : (m == 1) ? W1b : (m == 2) ? W1c : W1d;
    w1t[idx] = f2bf(W1[k * DD + j]);
}

// ---------------------------------------------------------------------------
// Fused 4-MLP kernel — r10 validated compute path with 3 M-fragments per wave
// (48 edges/wave, 192/block @ 4 waves): staging / layer-1 reads / w2 reads /
// barriers per edge all /1.5, while register demand (~152) stays under the
// 3-waves/SIMD cliff (~170) that killed r12 (196 VGPR -> 2/SIMD). WPAD=140
// (r12-verified conflict fix) + b1 in LDS (r11-verified). Per-edge numerics
// identical to r10.
// ---------------------------------------------------------------------------
__global__ __launch_bounds__(256) void mlp_mfma_kernel(
    const float* __restrict__ latent, const unsigned short* __restrict__ w1t,
    const float* __restrict__ va, const float* __restrict__ vb, const float* __restrict__ vc,
    float* __restrict__ out, float* __restrict__ lam_ws, MlpArgs args)
{
    __shared__ unsigned short Ws[DD * WPAD];  // 35.8 KB
    __shared__ float W2s[DD * 3];             // 1.5 KB
    __shared__ float B1s[DD];                 // 0.5 KB
    __shared__ float Cf[4][48][10];           // 7.7 KB

    const int t = threadIdx.x;
    const int wave = t >> 6, l = t & 63;
    const int lg = l >> 4, lr = l & 15;       // 16-lane group id / lane-in-group
    const int e0 = blockIdx.x * EPB + wave * 48;

    // ---- A fragments: a[mf][kc], edge row = lr (+16*mf), k = lg*8 + kc*32 + b
    s16x8 a[3][4];
    #pragma unroll
    for (int mf = 0; mf < 3; ++mf) {
        int e = e0 + mf * 16 + lr; if (e >= NE) e = NE - 1;
        const float* src = latent + (size_t)e * DD + lg * 8;
        #pragma unroll
        for (int kc = 0; kc < 4; ++kc) {
            float4 x0 = *(const float4*)(src + kc * 32);
            float4 x1 = *(const float4*)(src + kc * 32 + 4);
            s16x8 v;
            v[0] = (short)f2bf(x0.x); v[1] = (short)f2bf(x0.y);
            v[2] = (short)f2bf(x0.z); v[3] = (short)f2bf(x0.w);
            v[4] = (short)f2bf(x1.x); v[5] = (short)f2bf(x1.y);
            v[6] = (short)f2bf(x1.z); v[7] = (short)f2bf(x1.w);
            a[mf][kc] = v;
        }
    }

    for (int m = 0; m < 4; ++m) {
        const MlpPtrs P = args.m[m];
        __syncthreads();                       // everyone done with previous Ws
        // stage W1T panel (32 KB = 2048 uint4) — coalesced dwordx4, padded ds_write
        {
            const uint4* src = (const uint4*)(w1t + m * DD * DD);
            #pragma unroll
            for (int i = 0; i < 8; ++i) {                  // 8*256 = 2048 units
                int idx16 = t + i * 256;                   // 16-byte units
                uint4 vv = src[idx16];
                int j = idx16 >> 4, k = (idx16 & 15) * 8;  // 16 units per 128-short row
                *(uint4*)&Ws[j * WPAD + k] = vv;
            }
        }
        for (int i = t; i < DD * P.dout; i += 256) W2s[i] = P.W2[i];
        if (t < DD) B1s[t] = P.b1[t];
        __syncthreads();

        // ---- layer 1: MFMA (each W-fragment read feeds 3 MFMAs)
        f32x4 acc[3][8];
        #pragma unroll
        for (int mf = 0; mf < 3; ++mf)
            #pragma unroll
            for (int nf = 0; nf < 8; ++nf) {
                f32x4 z = {0.f, 0.f, 0.f, 0.f};
                acc[mf][nf] = z;
            }
        #pragma unroll
        for (int nf = 0; nf < 8; ++nf) {
            #pragma unroll
            for (int kc = 0; kc < 4; ++kc) {
                s16x8 b = *(const s16x8*)&Ws[(lr + 16 * nf) * WPAD + lg * 8 + kc * 32];
                acc[0][nf] = __builtin_amdgcn_mfma_f32_16x16x32_bf16(a[0][kc], b, acc[0][nf], 0, 0, 0);
                acc[1][nf] = __builtin_amdgcn_mfma_f32_16x16x32_bf16(a[1][kc], b, acc[1][nf], 0, 0, 0);
                acc[2][nf] = __builtin_amdgcn_mfma_f32_16x16x32_bf16(a[2][kc], b, acc[2][nf], 0, 0, 0);
            }
        }
        // bias + relu  (C layout: col j = lr + 16*nf, row = mf*16 + lg*4 + r)
        #pragma unroll
        for (int nf = 0; nf < 8; ++nf) {
            float bv = B1s[16 * nf + lr];
            #pragma unroll
            for (int mf = 0; mf < 3; ++mf)
                #pragma unroll
                for (int r = 0; r < 4; ++r)
                    acc[mf][nf][r] = fmaxf(acc[mf][nf][r] + bv, 0.f);
        }
        // ---- layer 2: coeff[e][o] = sum_j h[e][j] W2[j][o] + b2[o]
        for (int o = 0; o < P.dout; ++o) {
            float w2v[8];
            #pragma unroll
            for (int nf = 0; nf < 8; ++nf) w2v[nf] = W2s[(16 * nf + lr) * P.dout + o];
            float p[3][4];
            #pragma unroll
            for (int mf = 0; mf < 3; ++mf)
                #pragma unroll
                for (int r = 0; r < 4; ++r) {
                    float s = 0.f;
                    #pragma unroll
                    for (int nf = 0; nf < 8; ++nf) s = fmaf(acc[mf][nf][r], w2v[nf], s);
                    s += __shfl_xor(s, 8);
                    s += __shfl_xor(s, 4);
                    s += __shfl_xor(s, 2);
                    s += __shfl_xor(s, 1);
                    p[mf][r] = s;
                }
            if (lr == 0) {
                float b2v = P.b2[o];
                #pragma unroll
                for (int mf = 0; mf < 3; ++mf)
                    #pragma unroll
                    for (int r = 0; r < 4; ++r)
                        Cf[wave][mf * 16 + lg * 4 + r][P.obase + o] = p[mf][r] + b2v;
            }
        }
    }
    __syncthreads();

    // ---- epilogue: combine coeffs with vectors (lanes l<48 own one edge)
    if (l < 48) {
        const int e = e0 + l;
        if (e < NE) {
            float c[10];
            #pragma unroll
            for (int q = 0; q < 10; ++q) c[q] = Cf[wave][l][q];
            const float ax = va[(size_t)e*3+0], ay = va[(size_t)e*3+1], az = va[(size_t)e*3+2];
            const float bx = vb[(size_t)e*3+0], by = vb[(size_t)e*3+1], bz = vb[(size_t)e*3+2];
            const float cx = vc[(size_t)e*3+0], cy = vc[(size_t)e*3+1], cz = vc[(size_t)e*3+2];
            const size_t o0 = (size_t)e * 3;
            const size_t o1 = (size_t)NE * 3 + o0;
            const size_t o2 = (size_t)2 * NE * 3 + o0;
            out[o0+0] = c[0]*ax + c[1]*bx + c[2]*cx;
            out[o0+1] = c[0]*ay + c[1]*by + c[2]*cy;
            out[o0+2] = c[0]*az + c[1]*bz + c[2]*cz;
            out[o1+0] = c[3]*ax + c[4]*bx + c[5]*cx;
            out[o1+1] = c[3]*ay + c[4]*by + c[5]*cy;
            out[o1+2] = c[3]*az + c[4]*bz + c[5]*cz;
            out[o2+0] = c[7]*ax + c[8]*bx + c[9]*cx;
            out[o2+1] = c[7]*ay + c[8]*by + c[9]*cy;
            out[o2+2] = c[7]*az + c[8]*bz + c[9]*cz;
            lam_ws[e] = c[6];
        }
    }
}

// ---------------------------------------------------------------------------
__global__ void zero_kernel(float* __restrict__ p, int n)
{
    int i = blockIdx.x * blockDim.x + threadIdx.x;
    if (i < n) p[i] = 0.0f;
}

// pass 1: segment sums over mask_in (receivers)
__global__ void seg_sum_kernel(const int* __restrict__ idx, const int* __restrict__ edge_attr,
                               const int* __restrict__ node_type, const float* __restrict__ out,
                               float* __restrict__ sums, float* __restrict__ cnt)
{
    int e = blockIdx.x * blockDim.x + threadIdx.x;
    if (e >= NE) return;
    if (edge_attr[e] != -1) return;
    const int n = idx[e];
    if (node_type[2 * n + 1] != -1) return;
    atomicAdd(&cnt[n], 1.0f);
    #pragma unroll
    for (int tns = 0; tns < 3; ++tns)
        #pragma unroll
        for (int c2 = 0; c2 < 3; ++c2)
            atomicAdd(&sums[(size_t)tns * 3 * NN + (size_t)n * 3 + c2],
                      out[(size_t)tns * NE * 3 + (size_t)e * 3 + c2]);
}

// fused: apply receiver-mean subtraction, then accumulate sender-mask sums
__global__ void apply_r_sum_s_kernel(const int* __restrict__ senders, const int* __restrict__ receivers,
                                     const int* __restrict__ edge_attr, const int* __restrict__ node_type,
                                     float* __restrict__ out,
                                     const float* __restrict__ sIn, const float* __restrict__ cIn,
                                     float* __restrict__ sOut, float* __restrict__ cOut)
{
    int e = blockIdx.x * blockDim.x + threadIdx.x;
    if (e >= NE) return;
    if (edge_attr[e] != -1) return;                // both masks require virtual
    const int r = receivers[e], s = senders[e];
    const bool mr = (node_type[2 * r + 1] == -1);
    const bool ms = (node_type[2 * s + 1] == -1);
    if (!mr && !ms) return;
    float v[9];
    #pragma unroll
    for (int tns = 0; tns < 3; ++tns)
        #pragma unroll
        for (int c2 = 0; c2 < 3; ++c2)
            v[tns * 3 + c2] = out[(size_t)tns * NE * 3 + (size_t)e * 3 + c2];
    if (mr) {
        const float ic = 1.0f / fmaxf(cIn[r], 1.0f);
        #pragma unroll
        for (int tns = 0; tns < 3; ++tns)
            #pragma unroll
            for (int c2 = 0; c2 < 3; ++c2) {
                v[tns * 3 + c2] -= sIn[(size_t)tns * 3 * NN + (size_t)r * 3 + c2] * ic;
                out[(size_t)tns * NE * 3 + (size_t)e * 3 + c2] = v[tns * 3 + c2];
            }
    }
    if (ms) {
        atomicAdd(&cOut[s], 1.0f);
        #pragma unroll
        for (int tns = 0; tns < 3; ++tns)
            #pragma unroll
            for (int c2 = 0; c2 < 3; ++c2)
                atomicAdd(&sOut[(size_t)tns * 3 * NN + (size_t)s * 3 + c2], v[tns * 3 + c2]);
    }
}

// pass-2 subtract (senders mask) fused with tau finalize
__global__ void apply_finalize_kernel(const int* __restrict__ senders, const int* __restrict__ receivers,
                                      const int* __restrict__ edge_attr, const int* __restrict__ node_type,
                                      const float* __restrict__ sp, const float* __restrict__ rp,
                                      const float* __restrict__ wn, const float* __restrict__ lam,
                                      const float* __restrict__ sums, const float* __restrict__ cnt,
                                      float* __restrict__ out)
{
    int e = blockIdx.x * blockDim.x + threadIdx.x;
    if (e >= NE) return;
    const int s = senders[e], r = receivers[e];
    const size_t b = (size_t)e * 3;
    const size_t tb = (size_t)NE * 3 + b;
    const size_t db = (size_t)2 * NE * 3 + b;
    float fx = out[b+0], fy = out[b+1], fz = out[b+2];
    float axx = out[tb+0], ayy = out[tb+1], azz = out[tb+2];
    const bool masked = (edge_attr[e] == -1) && (node_type[2 * s + 1] == -1);
    if (masked) {
        const float ic = 1.0f / fmaxf(cnt[s], 1.0f);
        fx -= sums[(size_t)0 * 3 * NN + (size_t)s * 3 + 0] * ic;
        fy -= sums[(size_t)0 * 3 * NN + (size_t)s * 3 + 1] * ic;
        fz -= sums[(size_t)0 * 3 * NN + (size_t)s * 3 + 2] * ic;
        axx -= sums[(size_t)1 * 3 * NN + (size_t)s * 3 + 0] * ic;
        ayy -= sums[(size_t)1 * 3 * NN + (size_t)s * 3 + 1] * ic;
        azz -= sums[(size_t)1 * 3 * NN + (size_t)s * 3 + 2] * ic;
        out[b+0] = fx; out[b+1] = fy; out[b+2] = fz;
        out[db+0] -= sums[(size_t)2 * 3 * NN + (size_t)s * 3 + 0] * ic;
        out[db+1] -= sums[(size_t)2 * 3 * NN + (size_t)s * 3 + 1] * ic;
        out[db+2] -= sums[(size_t)2 * 3 * NN + (size_t)s * 3 + 2] * ic;
    }
    const float wsv = wn[s], wrv = wn[r];
    const float inv = 1.0f / (wsv + wrv);
    const float spx = sp[b+0], spy = sp[b+1], spz = sp[b+2];
    const float rpx = rp[b+0], rpy = rp[b+1], rpz = rp[b+2];
    const float lx = rpx - (wsv * spx + wrv * rpx) * inv;
    const float ly = rpy - (wsv * spy + wrv * rpy) * inv;
    const float lz = rpz - (wsv * spz + wrv * rpz) * inv;
    const float lv = lam[e];
    const float gx = fx * lv, gy = fy * lv, gz = fz * lv;
    out[tb+0] = axx - (ly * gz - lz * gy);
    out[tb+1] = ayy - (lz * gx - lx * gz);
    out[tb+2] = azz - (lx * gy - ly * gx);
}

// ---------------------------------------------------------------------------
extern "C" void kernel_launch(void* const* d_in, const int* in_sizes, int n_in,
                              void* d_out, int out_size, void* d_ws, size_t ws_size,
                              hipStream_t stream)
{
    (void)in_sizes; (void)n_in; (void)out_size; (void)ws_size;

    const int* edge_index    = (const int*)d_in[0];
    const int* edge_attr     = (const int*)d_in[1];
    const int* node_type     = (const int*)d_in[2];
    const float* senders_pos = (const float*)d_in[3];
    const float* recv_pos    = (const float*)d_in[4];
    const float* vector_a    = (const float*)d_in[5];
    const float* vector_b    = (const float*)d_in[6];
    const float* vector_c    = (const float*)d_in[7];
    const float* latent      = (const float*)d_in[8];
    const float* w_nodes     = (const float*)d_in[9];

    MlpArgs ma;
    const int douts[4] = {3, 3, 1, 3};
    const int obase[4] = {0, 3, 6, 7};
    for (int i = 0; i < 4; ++i) {
        ma.m[i].W1 = (const float*)d_in[10 + i * 4 + 0];
        ma.m[i].b1 = (const float*)d_in[10 + i * 4 + 1];
        ma.m[i].W2 = (const float*)d_in[10 + i * 4 + 2];
        ma.m[i].b2 = (const float*)d_in[10 + i * 4 + 3];
        ma.m[i].dout = douts[i];
        ma.m[i].obase = obase[i];
    }

    float* out = (float*)d_out;
    // ws (floats): [lambda NE][sIn 9N][cIn N][sOut 9N][cOut N][w1t 32768 f-equiv]
    float* lam    = (float*)d_ws;
    float* segbuf = lam + NE;
    float* sIn    = segbuf;
    float* cIn    = sIn + 9 * NN;
    float* sOut   = cIn + NN;
    float* cOut   = sOut + 9 * NN;
    unsigned short* w1t = (unsigned short*)(cOut + NN);

    const int* senders   = edge_index;
    const int* receivers = edge_index + NE;

    hipLaunchKernelGGL(prep_w1t_kernel, dim3((4 * DD * DD + 255) / 256), dim3(256), 0, stream,
                       ma.m[0].W1, ma.m[1].W1, ma.m[2].W1, ma.m[3].W1, w1t);
    hipLaunchKernelGGL(zero_kernel, dim3((20 * NN + 255) / 256), dim3(256), 0, stream,
                       segbuf, 20 * NN);
    hipLaunchKernelGGL(mlp_mfma_kernel, dim3((NE + EPB - 1) / EPB), dim3(256), 0, stream,
                       latent, w1t, vector_a, vector_b, vector_c, out, lam, ma);
    dim3 gE((NE + 255) / 256);
    hipLaunchKernelGGL(seg_sum_kernel,       gE, dim3(256), 0, stream, receivers, edge_attr, node_type, out, sIn, cIn);
    hipLaunchKernelGGL(apply_r_sum_s_kernel, gE, dim3(256), 0, stream, senders, receivers, edge_attr, node_type,
                       out, sIn, cIn, sOut, cOut);
    hipLaunchKernelGGL(apply_finalize_kernel, gE, dim3(256), 0, stream, senders, receivers, edge_attr, node_type,
                       senders_pos, recv_pos, w_nodes, lam, sOut, cOut, out);
}

// Round 14
// 297.752 us; speedup vs baseline: 1.2055x; 1.2055x over previous
//
#include <hip/hip_runtime.h>
#include <hip/hip_bf16.h>

#define NN 50000     // nodes
#define NE 500000    // edges
#define DD 128       // latent size
#define WPAD 140     // Ws row pad (shorts): 280 B = 70 dw == 6 mod 32 -> ~2-way banks

typedef float  f32x4 __attribute__((ext_vector_type(4)));
typedef short  s16x8 __attribute__((ext_vector_type(8)));

struct MlpPtrs { const float* W1; const float* b1; const float* W2; const float* b2; int dout; int obase; };
struct MlpArgs { MlpPtrs m[4]; };

__device__ __forceinline__ unsigned short f2bf(float f) {
    unsigned int u = __builtin_bit_cast(unsigned int, f);
    u += 0x7fffu + ((u >> 16) & 1u);           // RNE
    return (unsigned short)(u >> 16);
}

// ---------------------------------------------------------------------------
// Prep: W1T bf16 [m][j][k]  (transposed so B-fragments read 8 contiguous k)
// ---------------------------------------------------------------------------
__global__ void prep_w1t_kernel(const float* __restrict__ W1a, const float* __restrict__ W1b,
                                const float* __restrict__ W1c, const float* __restrict__ W1d,
                                unsigned short* __restrict__ w1t)
{
    int idx = blockIdx.x * blockDim.x + threadIdx.x;   // 4*128*128
    if (idx >= 4 * DD * DD) return;
    int m = idx >> 14, r = idx & 16383;
    int j = r >> 7, k = r & 127;
    const float* W1 = (m == 0) ? W1a : (m == 1) ? W1b : (m == 2) ? W1c : W1d;
    w1t[idx] = f2bf(W1[k * DD + j]);
}

// ---------------------------------------------------------------------------
// Fused 4-MLP kernel — EXACT r10 validated structure (4 waves / 128 edges /
// block, 2 M-frags per wave, 112-VGPR bucket) + two pre-validated
// value-identical fixes: WPAD=140 row pad (r12/r13: conflicts 8M->2M) and
// b1 staged to LDS (r11-r13). M-frag scaling >2 is dead: >128 VGPR halves
// occupancy (r12: 196 VGPR -> 11.4%, r13: 172 -> 10.9%, both regressed).
// ---------------------------------------------------------------------------
__global__ __launch_bounds__(256) void mlp_mfma_kernel(
    const float* __restrict__ latent, const unsigned short* __restrict__ w1t,
    const float* __restrict__ va, const float* __restrict__ vb, const float* __restrict__ vc,
    float* __restrict__ out, float* __restrict__ lam_ws, MlpArgs args)
{
    __shared__ unsigned short Ws[DD * WPAD];  // 35.8 KB
    __shared__ float W2s[DD * 3];             // 1.5 KB
    __shared__ float B1s[DD];                 // 0.5 KB
    __shared__ float Cf[4][32][10];           // 5 KB

    const int t = threadIdx.x;
    const int wave = t >> 6, l = t & 63;
    const int lg = l >> 4, lr = l & 15;       // 16-lane group id / lane-in-group
    const int e0 = blockIdx.x * 128 + wave * 32;

    // ---- A fragments: a[mf][kc], edge row = lr (+16*mf), k = lg*8 + kc*32 + b
    s16x8 a[2][4];
    #pragma unroll
    for (int mf = 0; mf < 2; ++mf) {
        int e = e0 + mf * 16 + lr; if (e >= NE) e = NE - 1;
        const float* src = latent + (size_t)e * DD + lg * 8;
        #pragma unroll
        for (int kc = 0; kc < 4; ++kc) {
            float4 x0 = *(const float4*)(src + kc * 32);
            float4 x1 = *(const float4*)(src + kc * 32 + 4);
            s16x8 v;
            v[0] = (short)f2bf(x0.x); v[1] = (short)f2bf(x0.y);
            v[2] = (short)f2bf(x0.z); v[3] = (short)f2bf(x0.w);
            v[4] = (short)f2bf(x1.x); v[5] = (short)f2bf(x1.y);
            v[6] = (short)f2bf(x1.z); v[7] = (short)f2bf(x1.w);
            a[mf][kc] = v;
        }
    }

    for (int m = 0; m < 4; ++m) {
        const MlpPtrs P = args.m[m];
        __syncthreads();                       // everyone done with previous Ws
        // stage W1T panel (32 KB = 2048 uint4) — coalesced dwordx4, padded ds_write
        {
            const uint4* src = (const uint4*)(w1t + m * DD * DD);
            #pragma unroll
            for (int i = 0; i < 8; ++i) {                  // 8*256 = 2048 units
                int idx16 = t + i * 256;                   // 16-byte units
                uint4 vv = src[idx16];
                int j = idx16 >> 4, k = (idx16 & 15) * 8;  // 16 units per 128-short row
                *(uint4*)&Ws[j * WPAD + k] = vv;
            }
        }
        for (int i = t; i < DD * P.dout; i += 256) W2s[i] = P.W2[i];
        if (t < DD) B1s[t] = P.b1[t];
        __syncthreads();

        // ---- layer 1: MFMA
        f32x4 acc[2][8];
        #pragma unroll
        for (int mf = 0; mf < 2; ++mf)
            #pragma unroll
            for (int nf = 0; nf < 8; ++nf) {
                f32x4 z = {0.f, 0.f, 0.f, 0.f};
                acc[mf][nf] = z;
            }
        #pragma unroll
        for (int nf = 0; nf < 8; ++nf) {
            #pragma unroll
            for (int kc = 0; kc < 4; ++kc) {
                s16x8 b = *(const s16x8*)&Ws[(lr + 16 * nf) * WPAD + lg * 8 + kc * 32];
                acc[0][nf] = __builtin_amdgcn_mfma_f32_16x16x32_bf16(a[0][kc], b, acc[0][nf], 0, 0, 0);
                acc[1][nf] = __builtin_amdgcn_mfma_f32_16x16x32_bf16(a[1][kc], b, acc[1][nf], 0, 0, 0);
            }
        }
        // bias + relu  (C layout: col j = lr + 16*nf, row = mf*16 + lg*4 + r)
        #pragma unroll
        for (int nf = 0; nf < 8; ++nf) {
            float bv = B1s[16 * nf + lr];
            #pragma unroll
            for (int mf = 0; mf < 2; ++mf)
                #pragma unroll
                for (int r = 0; r < 4; ++r)
                    acc[mf][nf][r] = fmaxf(acc[mf][nf][r] + bv, 0.f);
        }
        // ---- layer 2: coeff[e][o] = sum_j h[e][j] W2[j][o] + b2[o]
        for (int o = 0; o < P.dout; ++o) {
            float w2v[8];
            #pragma unroll
            for (int nf = 0; nf < 8; ++nf) w2v[nf] = W2s[(16 * nf + lr) * P.dout + o];
            float p[2][4];
            #pragma unroll
            for (int mf = 0; mf < 2; ++mf)
                #pragma unroll
                for (int r = 0; r < 4; ++r) {
                    float s = 0.f;
                    #pragma unroll
                    for (int nf = 0; nf < 8; ++nf) s = fmaf(acc[mf][nf][r], w2v[nf], s);
                    s += __shfl_xor(s, 8);
                    s += __shfl_xor(s, 4);
                    s += __shfl_xor(s, 2);
                    s += __shfl_xor(s, 1);
                    p[mf][r] = s;
                }
            if (lr == 0) {
                float b2v = P.b2[o];
                #pragma unroll
                for (int mf = 0; mf < 2; ++mf)
                    #pragma unroll
                    for (int r = 0; r < 4; ++r)
                        Cf[wave][mf * 16 + lg * 4 + r][P.obase + o] = p[mf][r] + b2v;
            }
        }
    }
    __syncthreads();

    // ---- epilogue: combine coeffs with vectors
    if (l < 32) {
        const int e = e0 + l;
        if (e < NE) {
            float c[10];
            #pragma unroll
            for (int q = 0; q < 10; ++q) c[q] = Cf[wave][l][q];
            const float ax = va[(size_t)e*3+0], ay = va[(size_t)e*3+1], az = va[(size_t)e*3+2];
            const float bx = vb[(size_t)e*3+0], by = vb[(size_t)e*3+1], bz = vb[(size_t)e*3+2];
            const float cx = vc[(size_t)e*3+0], cy = vc[(size_t)e*3+1], cz = vc[(size_t)e*3+2];
            const size_t o0 = (size_t)e * 3;
            const size_t o1 = (size_t)NE * 3 + o0;
            const size_t o2 = (size_t)2 * NE * 3 + o0;
            out[o0+0] = c[0]*ax + c[1]*bx + c[2]*cx;
            out[o0+1] = c[0]*ay + c[1]*by + c[2]*cy;
            out[o0+2] = c[0]*az + c[1]*bz + c[2]*cz;
            out[o1+0] = c[3]*ax + c[4]*bx + c[5]*cx;
            out[o1+1] = c[3]*ay + c[4]*by + c[5]*cy;
            out[o1+2] = c[3]*az + c[4]*bz + c[5]*cz;
            out[o2+0] = c[7]*ax + c[8]*bx + c[9]*cx;
            out[o2+1] = c[7]*ay + c[8]*by + c[9]*cy;
            out[o2+2] = c[7]*az + c[8]*bz + c[9]*cz;
            lam_ws[e] = c[6];
        }
    }
}

// ---------------------------------------------------------------------------
__global__ void zero_kernel(float* __restrict__ p, int n)
{
    int i = blockIdx.x * blockDim.x + threadIdx.x;
    if (i < n) p[i] = 0.0f;
}

// pass 1: segment sums over mask_in (receivers)
__global__ void seg_sum_kernel(const int* __restrict__ idx, const int* __restrict__ edge_attr,
                               const int* __restrict__ node_type, const float* __restrict__ out,
                               float* __restrict__ sums, float* __restrict__ cnt)
{
    int e = blockIdx.x * blockDim.x + threadIdx.x;
    if (e >= NE) return;
    if (edge_attr[e] != -1) return;
    const int n = idx[e];
    if (node_type[2 * n + 1] != -1) return;
    atomicAdd(&cnt[n], 1.0f);
    #pragma unroll
    for (int tns = 0; tns < 3; ++tns)
        #pragma unroll
        for (int c2 = 0; c2 < 3; ++c2)
            atomicAdd(&sums[(size_t)tns * 3 * NN + (size_t)n * 3 + c2],
                      out[(size_t)tns * NE * 3 + (size_t)e * 3 + c2]);
}

// fused: apply receiver-mean subtraction, then accumulate sender-mask sums
__global__ void apply_r_sum_s_kernel(const int* __restrict__ senders, const int* __restrict__ receivers,
                                     const int* __restrict__ edge_attr, const int* __restrict__ node_type,
                                     float* __restrict__ out,
                                     const float* __restrict__ sIn, const float* __restrict__ cIn,
                                     float* __restrict__ sOut, float* __restrict__ cOut)
{
    int e = blockIdx.x * blockDim.x + threadIdx.x;
    if (e >= NE) return;
    if (edge_attr[e] != -1) return;                // both masks require virtual
    const int r = receivers[e], s = senders[e];
    const bool mr = (node_type[2 * r + 1] == -1);
    const bool ms = (node_type[2 * s + 1] == -1);
    if (!mr && !ms) return;
    float v[9];
    #pragma unroll
    for (int tns = 0; tns < 3; ++tns)
        #pragma unroll
        for (int c2 = 0; c2 < 3; ++c2)
            v[tns * 3 + c2] = out[(size_t)tns * NE * 3 + (size_t)e * 3 + c2];
    if (mr) {
        const float ic = 1.0f / fmaxf(cIn[r], 1.0f);
        #pragma unroll
        for (int tns = 0; tns < 3; ++tns)
            #pragma unroll
            for (int c2 = 0; c2 < 3; ++c2) {
                v[tns * 3 + c2] -= sIn[(size_t)tns * 3 * NN + (size_t)r * 3 + c2] * ic;
                out[(size_t)tns * NE * 3 + (size_t)e * 3 + c2] = v[tns * 3 + c2];
            }
    }
    if (ms) {
        atomicAdd(&cOut[s], 1.0f);
        #pragma unroll
        for (int tns = 0; tns < 3; ++tns)
            #pragma unroll
            for (int c2 = 0; c2 < 3; ++c2)
                atomicAdd(&sOut[(size_t)tns * 3 * NN + (size_t)s * 3 + c2], v[tns * 3 + c2]);
    }
}

// pass-2 subtract (senders mask) fused with tau finalize
__global__ void apply_finalize_kernel(const int* __restrict__ senders, const int* __restrict__ receivers,
                                      const int* __restrict__ edge_attr, const int* __restrict__ node_type,
                                      const float* __restrict__ sp, const float* __restrict__ rp,
                                      const float* __restrict__ wn, const float* __restrict__ lam,
                                      const float* __restrict__ sums, const float* __restrict__ cnt,
                                      float* __restrict__ out)
{
    int e = blockIdx.x * blockDim.x + threadIdx.x;
    if (e >= NE) return;
    const int s = senders[e], r = receivers[e];
    const size_t b = (size_t)e * 3;
    const size_t tb = (size_t)NE * 3 + b;
    const size_t db = (size_t)2 * NE * 3 + b;
    float fx = out[b+0], fy = out[b+1], fz = out[b+2];
    float axx = out[tb+0], ayy = out[tb+1], azz = out[tb+2];
    const bool masked = (edge_attr[e] == -1) && (node_type[2 * s + 1] == -1);
    if (masked) {
        const float ic = 1.0f / fmaxf(cnt[s], 1.0f);
        fx -= sums[(size_t)0 * 3 * NN + (size_t)s * 3 + 0] * ic;
        fy -= sums[(size_t)0 * 3 * NN + (size_t)s * 3 + 1] * ic;
        fz -= sums[(size_t)0 * 3 * NN + (size_t)s * 3 + 2] * ic;
        axx -= sums[(size_t)1 * 3 * NN + (size_t)s * 3 + 0] * ic;
        ayy -= sums[(size_t)1 * 3 * NN + (size_t)s * 3 + 1] * ic;
        azz -= sums[(size_t)1 * 3 * NN + (size_t)s * 3 + 2] * ic;
        out[b+0] = fx; out[b+1] = fy; out[b+2] = fz;
        out[db+0] -= sums[(size_t)2 * 3 * NN + (size_t)s * 3 + 0] * ic;
        out[db+1] -= sums[(size_t)2 * 3 * NN + (size_t)s * 3 + 1] * ic;
        out[db+2] -= sums[(size_t)2 * 3 * NN + (size_t)s * 3 + 2] * ic;
    }
    const float wsv = wn[s], wrv = wn[r];
    const float inv = 1.0f / (wsv + wrv);
    const float spx = sp[b+0], spy = sp[b+1], spz = sp[b+2];
    const float rpx = rp[b+0], rpy = rp[b+1], rpz = rp[b+2];
    const float lx = rpx - (wsv * spx + wrv * rpx) * inv;
    const float ly = rpy - (wsv * spy + wrv * rpy) * inv;
    const float lz = rpz - (wsv * spz + wrv * rpz) * inv;
    const float lv = lam[e];
    const float gx = fx * lv, gy = fy * lv, gz = fz * lv;
    out[tb+0] = axx - (ly * gz - lz * gy);
    out[tb+1] = ayy - (lz * gx - lx * gz);
    out[tb+2] = azz - (lx * gy - ly * gx);
}

// ---------------------------------------------------------------------------
extern "C" void kernel_launch(void* const* d_in, const int* in_sizes, int n_in,
                              void* d_out, int out_size, void* d_ws, size_t ws_size,
                              hipStream_t stream)
{
    (void)in_sizes; (void)n_in; (void)out_size; (void)ws_size;

    const int* edge_index    = (const int*)d_in[0];
    const int* edge_attr     = (const int*)d_in[1];
    const int* node_type     = (const int*)d_in[2];
    const float* senders_pos = (const float*)d_in[3];
    const float* recv_pos    = (const float*)d_in[4];
    const float* vector_a    = (const float*)d_in[5];
    const float* vector_b    = (const float*)d_in[6];
    const float* vector_c    = (const float*)d_in[7];
    const float* latent      = (const float*)d_in[8];
    const float* w_nodes     = (const float*)d_in[9];

    MlpArgs ma;
    const int douts[4] = {3, 3, 1, 3};
    const int obase[4] = {0, 3, 6, 7};
    for (int i = 0; i < 4; ++i) {
        ma.m[i].W1 = (const float*)d_in[10 + i * 4 + 0];
        ma.m[i].b1 = (const float*)d_in[10 + i * 4 + 1];
        ma.m[i].W2 = (const float*)d_in[10 + i * 4 + 2];
        ma.m[i].b2 = (const float*)d_in[10 + i * 4 + 3];
        ma.m[i].dout = douts[i];
        ma.m[i].obase = obase[i];
    }

    float* out = (float*)d_out;
    // ws (floats): [lambda NE][sIn 9N][cIn N][sOut 9N][cOut N][w1t 32768 f-equiv]
    float* lam    = (float*)d_ws;
    float* segbuf = lam + NE;
    float* sIn    = segbuf;
    float* cIn    = sIn + 9 * NN;
    float* sOut   = cIn + NN;
    float* cOut   = sOut + 9 * NN;
    unsigned short* w1t = (unsigned short*)(cOut + NN);

    const int* senders   = edge_index;
    const int* receivers = edge_index + NE;

    hipLaunchKernelGGL(prep_w1t_kernel, dim3((4 * DD * DD + 255) / 256), dim3(256), 0, stream,
                       ma.m[0].W1, ma.m[1].W1, ma.m[2].W1, ma.m[3].W1, w1t);
    hipLaunchKernelGGL(zero_kernel, dim3((20 * NN + 255) / 256), dim3(256), 0, stream,
                       segbuf, 20 * NN);
    hipLaunchKernelGGL(mlp_mfma_kernel, dim3((NE + 127) / 128), dim3(256), 0, stream,
                       latent, w1t, vector_a, vector_b, vector_c, out, lam, ma);
    dim3 gE((NE + 255) / 256);
    hipLaunchKernelGGL(seg_sum_kernel,       gE, dim3(256), 0, stream, receivers, edge_attr, node_type, out, sIn, cIn);
    hipLaunchKernelGGL(apply_r_sum_s_kernel, gE, dim3(256), 0, stream, senders, receivers, edge_attr, node_type,
                       out, sIn, cIn, sOut, cOut);
    hipLaunchKernelGGL(apply_finalize_kernel, gE, dim3(256), 0, stream, senders, receivers, edge_attr, node_type,
                       senders_pos, recv_pos, w_nodes, lam, sOut, cOut, out);
}

// Round 15
// 255.571 us; speedup vs baseline: 1.4045x; 1.1650x over previous
//
#include <hip/hip_runtime.h>
#include <hip/hip_bf16.h>

#define NN 50000     // nodes
#define NE 500000    // edges
#define DD 128       // latent size

typedef float  f32x4 __attribute__((ext_vector_type(4)));
typedef short  s16x8 __attribute__((ext_vector_type(8)));

struct MlpPtrs { const float* W1; const float* b1; const float* W2; const float* b2; int dout; int obase; };
struct MlpArgs { MlpPtrs m[4]; };

__device__ __forceinline__ unsigned short f2bf(float f) {
    return __builtin_bit_cast(unsigned short, __hip_bfloat16(f));  // RNE; pairs fuse to v_cvt_pk_bf16_f32
}

// ---------------------------------------------------------------------------
// Prep: W1T bf16 [m][j][k]  (transposed so B-fragments read 8 contiguous k)
// ---------------------------------------------------------------------------
__global__ void prep_w1t_kernel(const float* __restrict__ W1a, const float* __restrict__ W1b,
                                const float* __restrict__ W1c, const float* __restrict__ W1d,
                                unsigned short* __restrict__ w1t)
{
    int idx = blockIdx.x * blockDim.x + threadIdx.x;   // 4*128*128
    if (idx >= 4 * DD * DD) return;
    int m = idx >> 14, r = idx & 16383;
    int j = r >> 7, k = r & 127;
    const float* W1 = (m == 0) ? W1a : (m == 1) ? W1b : (m == 2) ? W1c : W1d;
    w1t[idx] = f2bf(W1[k * DD + j]);
}

// ---------------------------------------------------------------------------
// Fused 4-MLP kernel — EXACT r10 validated structure (4 waves / 128 edges /
// block, 2 M-frags/wave, 136-short rows = 16B aligned; WPAD experiments dead:
// b128's 8-lane/bank-quad is inherent, and non-16B pads split b128 -> slower).
// Deltas vs r10: (1) f2bf via __hip_bfloat16 cast (r5/r7-validated, RNE
// bit-identical, fuses to v_cvt_pk_bf16_f32); (2) receivers-mask seg-sum
// fused into the epilogue (kills the separate seg_sum pass).
// ---------------------------------------------------------------------------
__global__ __launch_bounds__(256) void mlp_mfma_kernel(
    const float* __restrict__ latent, const unsigned short* __restrict__ w1t,
    const float* __restrict__ va, const float* __restrict__ vb, const float* __restrict__ vc,
    const int* __restrict__ receivers, const int* __restrict__ edge_attr,
    const int* __restrict__ node_type,
    float* __restrict__ out, float* __restrict__ lam_ws,
    float* __restrict__ sIn, float* __restrict__ cIn, MlpArgs args)
{
    __shared__ unsigned short Ws[DD * 136];   // 34.8 KB
    __shared__ float W2s[DD * 3];             // 1.5 KB
    __shared__ float Cf[4][32][10];           // 5 KB

    const int t = threadIdx.x;
    const int wave = t >> 6, l = t & 63;
    const int lg = l >> 4, lr = l & 15;       // 16-lane group id / lane-in-group
    const int e0 = blockIdx.x * 128 + wave * 32;

    // ---- A fragments: a[mf][kc], edge row = lr (+16*mf), k = lg*8 + kc*32 + b
    s16x8 a[2][4];
    #pragma unroll
    for (int mf = 0; mf < 2; ++mf) {
        int e = e0 + mf * 16 + lr; if (e >= NE) e = NE - 1;
        const float* src = latent + (size_t)e * DD + lg * 8;
        #pragma unroll
        for (int kc = 0; kc < 4; ++kc) {
            float4 x0 = *(const float4*)(src + kc * 32);
            float4 x1 = *(const float4*)(src + kc * 32 + 4);
            s16x8 v;
            v[0] = (short)f2bf(x0.x); v[1] = (short)f2bf(x0.y);
            v[2] = (short)f2bf(x0.z); v[3] = (short)f2bf(x0.w);
            v[4] = (short)f2bf(x1.x); v[5] = (short)f2bf(x1.y);
            v[6] = (short)f2bf(x1.z); v[7] = (short)f2bf(x1.w);
            a[mf][kc] = v;
        }
    }

    for (int m = 0; m < 4; ++m) {
        const MlpPtrs P = args.m[m];
        __syncthreads();                       // everyone done with previous Ws
        // stage W1T panel (32 KB = 2048 uint4) — coalesced dwordx4, padded ds_write
        {
            const uint4* src = (const uint4*)(w1t + m * DD * DD);
            #pragma unroll
            for (int i = 0; i < 8; ++i) {                  // 8*256 = 2048 units
                int idx16 = t + i * 256;                   // 16-byte units
                uint4 vv = src[idx16];
                int j = idx16 >> 4, k = (idx16 & 15) * 8;  // 16 units per 128-short row
                *(uint4*)&Ws[j * 136 + k] = vv;
            }
        }
        for (int i = t; i < DD * P.dout; i += 256) W2s[i] = P.W2[i];
        __syncthreads();

        // ---- layer 1: MFMA
        f32x4 acc[2][8];
        #pragma unroll
        for (int mf = 0; mf < 2; ++mf)
            #pragma unroll
            for (int nf = 0; nf < 8; ++nf) {
                f32x4 z = {0.f, 0.f, 0.f, 0.f};
                acc[mf][nf] = z;
            }
        #pragma unroll
        for (int nf = 0; nf < 8; ++nf) {
            #pragma unroll
            for (int kc = 0; kc < 4; ++kc) {
                s16x8 b = *(const s16x8*)&Ws[(lr + 16 * nf) * 136 + lg * 8 + kc * 32];
                acc[0][nf] = __builtin_amdgcn_mfma_f32_16x16x32_bf16(a[0][kc], b, acc[0][nf], 0, 0, 0);
                acc[1][nf] = __builtin_amdgcn_mfma_f32_16x16x32_bf16(a[1][kc], b, acc[1][nf], 0, 0, 0);
            }
        }
        // bias + relu  (C layout: col j = lr + 16*nf, row = mf*16 + lg*4 + r)
        #pragma unroll
        for (int nf = 0; nf < 8; ++nf) {
            float bv = P.b1[16 * nf + lr];
            #pragma unroll
            for (int mf = 0; mf < 2; ++mf)
                #pragma unroll
                for (int r = 0; r < 4; ++r)
                    acc[mf][nf][r] = fmaxf(acc[mf][nf][r] + bv, 0.f);
        }
        // ---- layer 2: coeff[e][o] = sum_j h[e][j] W2[j][o] + b2[o]
        for (int o = 0; o < P.dout; ++o) {
            float w2v[8];
            #pragma unroll
            for (int nf = 0; nf < 8; ++nf) w2v[nf] = W2s[(16 * nf + lr) * P.dout + o];
            float p[2][4];
            #pragma unroll
            for (int mf = 0; mf < 2; ++mf)
                #pragma unroll
                for (int r = 0; r < 4; ++r) {
                    float s = 0.f;
                    #pragma unroll
                    for (int nf = 0; nf < 8; ++nf) s = fmaf(acc[mf][nf][r], w2v[nf], s);
                    s += __shfl_xor(s, 8);
                    s += __shfl_xor(s, 4);
                    s += __shfl_xor(s, 2);
                    s += __shfl_xor(s, 1);
                    p[mf][r] = s;
                }
            if (lr == 0) {
                float b2v = P.b2[o];
                #pragma unroll
                for (int mf = 0; mf < 2; ++mf)
                    #pragma unroll
                    for (int r = 0; r < 4; ++r)
                        Cf[wave][mf * 16 + lg * 4 + r][P.obase + o] = p[mf][r] + b2v;
            }
        }
    }
    __syncthreads();

    // ---- epilogue: combine coeffs with vectors + fused receivers-mask seg-sum
    if (l < 32) {
        const int e = e0 + l;
        if (e < NE) {
            float c[10];
            #pragma unroll
            for (int q = 0; q < 10; ++q) c[q] = Cf[wave][l][q];
            const float ax = va[(size_t)e*3+0], ay = va[(size_t)e*3+1], az = va[(size_t)e*3+2];
            const float bx = vb[(size_t)e*3+0], by = vb[(size_t)e*3+1], bz = vb[(size_t)e*3+2];
            const float cx = vc[(size_t)e*3+0], cy = vc[(size_t)e*3+1], cz = vc[(size_t)e*3+2];
            const size_t o0 = (size_t)e * 3;
            const size_t o1 = (size_t)NE * 3 + o0;
            const size_t o2 = (size_t)2 * NE * 3 + o0;
            const float f0 = c[0]*ax + c[1]*bx + c[2]*cx;
            const float f1 = c[0]*ay + c[1]*by + c[2]*cy;
            const float f2 = c[0]*az + c[1]*bz + c[2]*cz;
            const float a0 = c[3]*ax + c[4]*bx + c[5]*cx;
            const float a1 = c[3]*ay + c[4]*by + c[5]*cy;
            const float a2 = c[3]*az + c[4]*bz + c[5]*cz;
            const float d0 = c[7]*ax + c[8]*bx + c[9]*cx;
            const float d1 = c[7]*ay + c[8]*by + c[9]*cy;
            const float d2 = c[7]*az + c[8]*bz + c[9]*cz;
            out[o0+0] = f0; out[o0+1] = f1; out[o0+2] = f2;
            out[o1+0] = a0; out[o1+1] = a1; out[o1+2] = a2;
            out[o2+0] = d0; out[o2+1] = d1; out[o2+2] = d2;
            lam_ws[e] = c[6];

            // fused pass-1 seg-sum: virtual edges into global receiver nodes
            if (edge_attr[e] == -1) {
                const int rn = receivers[e];
                if (node_type[2 * rn + 1] == -1) {
                    atomicAdd(&cIn[rn], 1.0f);
                    atomicAdd(&sIn[(size_t)0 * 3 * NN + (size_t)rn * 3 + 0], f0);
                    atomicAdd(&sIn[(size_t)0 * 3 * NN + (size_t)rn * 3 + 1], f1);
                    atomicAdd(&sIn[(size_t)0 * 3 * NN + (size_t)rn * 3 + 2], f2);
                    atomicAdd(&sIn[(size_t)1 * 3 * NN + (size_t)rn * 3 + 0], a0);
                    atomicAdd(&sIn[(size_t)1 * 3 * NN + (size_t)rn * 3 + 1], a1);
                    atomicAdd(&sIn[(size_t)1 * 3 * NN + (size_t)rn * 3 + 2], a2);
                    atomicAdd(&sIn[(size_t)2 * 3 * NN + (size_t)rn * 3 + 0], d0);
                    atomicAdd(&sIn[(size_t)2 * 3 * NN + (size_t)rn * 3 + 1], d1);
                    atomicAdd(&sIn[(size_t)2 * 3 * NN + (size_t)rn * 3 + 2], d2);
                }
            }
        }
    }
}

// ---------------------------------------------------------------------------
__global__ void zero_kernel(float* __restrict__ p, int n)
{
    int i = blockIdx.x * blockDim.x + threadIdx.x;
    if (i < n) p[i] = 0.0f;
}

// fused: apply receiver-mean subtraction, then accumulate sender-mask sums
__global__ void apply_r_sum_s_kernel(const int* __restrict__ senders, const int* __restrict__ receivers,
                                     const int* __restrict__ edge_attr, const int* __restrict__ node_type,
                                     float* __restrict__ out,
                                     const float* __restrict__ sIn, const float* __restrict__ cIn,
                                     float* __restrict__ sOut, float* __restrict__ cOut)
{
    int e = blockIdx.x * blockDim.x + threadIdx.x;
    if (e >= NE) return;
    if (edge_attr[e] != -1) return;                // both masks require virtual
    const int r = receivers[e], s = senders[e];
    const bool mr = (node_type[2 * r + 1] == -1);
    const bool ms = (node_type[2 * s + 1] == -1);
    if (!mr && !ms) return;
    float v[9];
    #pragma unroll
    for (int tns = 0; tns < 3; ++tns)
        #pragma unroll
        for (int c2 = 0; c2 < 3; ++c2)
            v[tns * 3 + c2] = out[(size_t)tns * NE * 3 + (size_t)e * 3 + c2];
    if (mr) {
        const float ic = 1.0f / fmaxf(cIn[r], 1.0f);
        #pragma unroll
        for (int tns = 0; tns < 3; ++tns)
            #pragma unroll
            for (int c2 = 0; c2 < 3; ++c2) {
                v[tns * 3 + c2] -= sIn[(size_t)tns * 3 * NN + (size_t)r * 3 + c2] * ic;
                out[(size_t)tns * NE * 3 + (size_t)e * 3 + c2] = v[tns * 3 + c2];
            }
    }
    if (ms) {
        atomicAdd(&cOut[s], 1.0f);
        #pragma unroll
        for (int tns = 0; tns < 3; ++tns)
            #pragma unroll
            for (int c2 = 0; c2 < 3; ++c2)
                atomicAdd(&sOut[(size_t)tns * 3 * NN + (size_t)s * 3 + c2], v[tns * 3 + c2]);
    }
}

// pass-2 subtract (senders mask) fused with tau finalize
__global__ void apply_finalize_kernel(const int* __restrict__ senders, const int* __restrict__ receivers,
                                      const int* __restrict__ edge_attr, const int* __restrict__ node_type,
                                      const float* __restrict__ sp, const float* __restrict__ rp,
                                      const float* __restrict__ wn, const float* __restrict__ lam,
                                      const float* __restrict__ sums, const float* __restrict__ cnt,
                                      float* __restrict__ out)
{
    int e = blockIdx.x * blockDim.x + threadIdx.x;
    if (e >= NE) return;
    const int s = senders[e], r = receivers[e];
    const size_t b = (size_t)e * 3;
    const size_t tb = (size_t)NE * 3 + b;
    const size_t db = (size_t)2 * NE * 3 + b;
    float fx = out[b+0], fy = out[b+1], fz = out[b+2];
    float axx = out[tb+0], ayy = out[tb+1], azz = out[tb+2];
    const bool masked = (edge_attr[e] == -1) && (node_type[2 * s + 1] == -1);
    if (masked) {
        const float ic = 1.0f / fmaxf(cnt[s], 1.0f);
        fx -= sums[(size_t)0 * 3 * NN + (size_t)s * 3 + 0] * ic;
        fy -= sums[(size_t)0 * 3 * NN + (size_t)s * 3 + 1] * ic;
        fz -= sums[(size_t)0 * 3 * NN + (size_t)s * 3 + 2] * ic;
        axx -= sums[(size_t)1 * 3 * NN + (size_t)s * 3 + 0] * ic;
        ayy -= sums[(size_t)1 * 3 * NN + (size_t)s * 3 + 1] * ic;
        azz -= sums[(size_t)1 * 3 * NN + (size_t)s * 3 + 2] * ic;
        out[b+0] = fx; out[b+1] = fy; out[b+2] = fz;
        out[db+0] -= sums[(size_t)2 * 3 * NN + (size_t)s * 3 + 0] * ic;
        out[db+1] -= sums[(size_t)2 * 3 * NN + (size_t)s * 3 + 1] * ic;
        out[db+2] -= sums[(size_t)2 * 3 * NN + (size_t)s * 3 + 2] * ic;
    }
    const float wsv = wn[s], wrv = wn[r];
    const float inv = 1.0f / (wsv + wrv);
    const float spx = sp[b+0], spy = sp[b+1], spz = sp[b+2];
    const float rpx = rp[b+0], rpy = rp[b+1], rpz = rp[b+2];
    const float lx = rpx - (wsv * spx + wrv * rpx) * inv;
    const float ly = rpy - (wsv * spy + wrv * rpy) * inv;
    const float lz = rpz - (wsv * spz + wrv * rpz) * inv;
    const float lv = lam[e];
    const float gx = fx * lv, gy = fy * lv, gz = fz * lv;
    out[tb+0] = axx - (ly * gz - lz * gy);
    out[tb+1] = ayy - (lz * gx - lx * gz);
    out[tb+2] = azz - (lx * gy - ly * gx);
}

// ---------------------------------------------------------------------------
extern "C" void kernel_launch(void* const* d_in, const int* in_sizes, int n_in,
                              void* d_out, int out_size, void* d_ws, size_t ws_size,
                              hipStream_t stream)
{
    (void)in_sizes; (void)n_in; (void)out_size; (void)ws_size;

    const int* edge_index    = (const int*)d_in[0];
    const int* edge_attr     = (const int*)d_in[1];
    const int* node_type     = (const int*)d_in[2];
    const float* senders_pos = (const float*)d_in[3];
    const float* recv_pos    = (const float*)d_in[4];
    const float* vector_a    = (const float*)d_in[5];
    const float* vector_b    = (const float*)d_in[6];
    const float* vector_c    = (const float*)d_in[7];
    const float* latent      = (const float*)d_in[8];
    const float* w_nodes     = (const float*)d_in[9];

    MlpArgs ma;
    const int douts[4] = {3, 3, 1, 3};
    const int obase[4] = {0, 3, 6, 7};
    for (int i = 0; i < 4; ++i) {
        ma.m[i].W1 = (const float*)d_in[10 + i * 4 + 0];
        ma.m[i].b1 = (const float*)d_in[10 + i * 4 + 1];
        ma.m[i].W2 = (const float*)d_in[10 + i * 4 + 2];
        ma.m[i].b2 = (const float*)d_in[10 + i * 4 + 3];
        ma.m[i].dout = douts[i];
        ma.m[i].obase = obase[i];
    }

    float* out = (float*)d_out;
    // ws (floats): [lambda NE][sIn 9N][cIn N][sOut 9N][cOut N][w1t 32768 f-equiv]
    float* lam    = (float*)d_ws;
    float* segbuf = lam + NE;
    float* sIn    = segbuf;
    float* cIn    = sIn + 9 * NN;
    float* sOut   = cIn + NN;
    float* cOut   = sOut + 9 * NN;
    unsigned short* w1t = (unsigned short*)(cOut + NN);

    const int* senders   = edge_index;
    const int* receivers = edge_index + NE;

    hipLaunchKernelGGL(prep_w1t_kernel, dim3((4 * DD * DD + 255) / 256), dim3(256), 0, stream,
                       ma.m[0].W1, ma.m[1].W1, ma.m[2].W1, ma.m[3].W1, w1t);
    hipLaunchKernelGGL(zero_kernel, dim3((20 * NN + 255) / 256), dim3(256), 0, stream,
                       segbuf, 20 * NN);
    hipLaunchKernelGGL(mlp_mfma_kernel, dim3((NE + 127) / 128), dim3(256), 0, stream,
                       latent, w1t, vector_a, vector_b, vector_c,
                       receivers, edge_attr, node_type, out, lam, sIn, cIn, ma);
    dim3 gE((NE + 255) / 256);
    hipLaunchKernelGGL(apply_r_sum_s_kernel, gE, dim3(256), 0, stream, senders, receivers, edge_attr, node_type,
                       out, sIn, cIn, sOut, cOut);
    hipLaunchKernelGGL(apply_finalize_kernel, gE, dim3(256), 0, stream, senders, receivers, edge_attr, node_type,
                       senders_pos, recv_pos, w_nodes, lam, sOut, cOut, out);
}

// Round 17
// 228.664 us; speedup vs baseline: 1.5698x; 1.1177x over previous
//
#include <hip/hip_runtime.h>
#include <hip/hip_bf16.h>

#define NN 50000     // nodes
#define NE 500000    // edges
#define DD 128       // latent size

typedef float  f32x4 __attribute__((ext_vector_type(4)));
typedef short  s16x8 __attribute__((ext_vector_type(8)));

struct MlpPtrs { const float* W1; const float* b1; const float* W2; const float* b2; int dout; int obase; };
struct MlpArgs { MlpPtrs m[4]; };

__device__ __forceinline__ unsigned short f2bf(float f) {
    return __builtin_bit_cast(unsigned short, __hip_bfloat16(f));  // RNE; pairs fuse to v_cvt_pk_bf16_f32
}

// Sum over the 16 lanes of each DPP row (lr-group) via row_ror rotate-reduce.
// 4 VALU v_add_f32_dpp ops — zero DS-pipe traffic (vs 4 ds_swizzle for
// shfl_xor). dpp_ctrl must be a literal, so the 4 steps are hand-unrolled.
// After this, ALL 16 lanes of the row hold the full sum.
__device__ __forceinline__ float row_reduce16(float v) {
    int x = __builtin_bit_cast(int, v);
    int y;
    float f;
    y = __builtin_amdgcn_update_dpp(0, x, 0x121, 0xf, 0xf, true);  // row_ror:1
    f = __builtin_bit_cast(float, x) + __builtin_bit_cast(float, y);
    x = __builtin_bit_cast(int, f);
    y = __builtin_amdgcn_update_dpp(0, x, 0x122, 0xf, 0xf, true);  // row_ror:2
    f = __builtin_bit_cast(float, x) + __builtin_bit_cast(float, y);
    x = __builtin_bit_cast(int, f);
    y = __builtin_amdgcn_update_dpp(0, x, 0x124, 0xf, 0xf, true);  // row_ror:4
    f = __builtin_bit_cast(float, x) + __builtin_bit_cast(float, y);
    x = __builtin_bit_cast(int, f);
    y = __builtin_amdgcn_update_dpp(0, x, 0x128, 0xf, 0xf, true);  // row_ror:8
    f = __builtin_bit_cast(float, x) + __builtin_bit_cast(float, y);
    return f;
}

// ---------------------------------------------------------------------------
// Prep: W1T bf16 [m][j][k]  (transposed so B-fragments read 8 contiguous k)
// ---------------------------------------------------------------------------
__global__ void prep_w1t_kernel(const float* __restrict__ W1a, const float* __restrict__ W1b,
                                const float* __restrict__ W1c, const float* __restrict__ W1d,
                                unsigned short* __restrict__ w1t)
{
    int idx = blockIdx.x * blockDim.x + threadIdx.x;   // 4*128*128
    if (idx >= 4 * DD * DD) return;
    int m = idx >> 14, r = idx & 16383;
    int j = r >> 7, k = r & 127;
    const float* W1 = (m == 0) ? W1a : (m == 1) ? W1b : (m == 2) ? W1c : W1d;
    w1t[idx] = f2bf(W1[k * DD + j]);
}

// ---------------------------------------------------------------------------
// Fused 4-MLP kernel — r15 validated structure (r10 compute + fused pass-1
// seg-sum in epilogue). Single delta vs r15: layer-2 reduction uses DPP
// row_ror rotate-reduce (VALU pipe) instead of shfl_xor butterfly (DS pipe),
// removing 320 DS ops per wave per tile from the shared DS bottleneck.
// ---------------------------------------------------------------------------
__global__ __launch_bounds__(256) void mlp_mfma_kernel(
    const float* __restrict__ latent, const unsigned short* __restrict__ w1t,
    const float* __restrict__ va, const float* __restrict__ vb, const float* __restrict__ vc,
    const int* __restrict__ receivers, const int* __restrict__ edge_attr,
    const int* __restrict__ node_type,
    float* __restrict__ out, float* __restrict__ lam_ws,
    float* __restrict__ sIn, float* __restrict__ cIn, MlpArgs args)
{
    __shared__ unsigned short Ws[DD * 136];   // 34.8 KB
    __shared__ float W2s[DD * 3];             // 1.5 KB
    __shared__ float Cf[4][32][10];           // 5 KB

    const int t = threadIdx.x;
    const int wave = t >> 6, l = t & 63;
    const int lg = l >> 4, lr = l & 15;       // 16-lane group id / lane-in-group
    const int e0 = blockIdx.x * 128 + wave * 32;

    // ---- A fragments: a[mf][kc], edge row = lr (+16*mf), k = lg*8 + kc*32 + b
    s16x8 a[2][4];
    #pragma unroll
    for (int mf = 0; mf < 2; ++mf) {
        int e = e0 + mf * 16 + lr; if (e >= NE) e = NE - 1;
        const float* src = latent + (size_t)e * DD + lg * 8;
        #pragma unroll
        for (int kc = 0; kc < 4; ++kc) {
            float4 x0 = *(const float4*)(src + kc * 32);
            float4 x1 = *(const float4*)(src + kc * 32 + 4);
            s16x8 v;
            v[0] = (short)f2bf(x0.x); v[1] = (short)f2bf(x0.y);
            v[2] = (short)f2bf(x0.z); v[3] = (short)f2bf(x0.w);
            v[4] = (short)f2bf(x1.x); v[5] = (short)f2bf(x1.y);
            v[6] = (short)f2bf(x1.z); v[7] = (short)f2bf(x1.w);
            a[mf][kc] = v;
        }
    }

    for (int m = 0; m < 4; ++m) {
        const MlpPtrs P = args.m[m];
        __syncthreads();                       // everyone done with previous Ws
        // stage W1T panel (32 KB = 2048 uint4) — coalesced dwordx4, padded ds_write
        {
            const uint4* src = (const uint4*)(w1t + m * DD * DD);
            #pragma unroll
            for (int i = 0; i < 8; ++i) {                  // 8*256 = 2048 units
                int idx16 = t + i * 256;                   // 16-byte units
                uint4 vv = src[idx16];
                int j = idx16 >> 4, k = (idx16 & 15) * 8;  // 16 units per 128-short row
                *(uint4*)&Ws[j * 136 + k] = vv;
            }
        }
        for (int i = t; i < DD * P.dout; i += 256) W2s[i] = P.W2[i];
        __syncthreads();

        // ---- layer 1: MFMA
        f32x4 acc[2][8];
        #pragma unroll
        for (int mf = 0; mf < 2; ++mf)
            #pragma unroll
            for (int nf = 0; nf < 8; ++nf) {
                f32x4 z = {0.f, 0.f, 0.f, 0.f};
                acc[mf][nf] = z;
            }
        #pragma unroll
        for (int nf = 0; nf < 8; ++nf) {
            #pragma unroll
            for (int kc = 0; kc < 4; ++kc) {
                s16x8 b = *(const s16x8*)&Ws[(lr + 16 * nf) * 136 + lg * 8 + kc * 32];
                acc[0][nf] = __builtin_amdgcn_mfma_f32_16x16x32_bf16(a[0][kc], b, acc[0][nf], 0, 0, 0);
                acc[1][nf] = __builtin_amdgcn_mfma_f32_16x16x32_bf16(a[1][kc], b, acc[1][nf], 0, 0, 0);
            }
        }
        // bias + relu  (C layout: col j = lr + 16*nf, row = mf*16 + lg*4 + r)
        #pragma unroll
        for (int nf = 0; nf < 8; ++nf) {
            float bv = P.b1[16 * nf + lr];
            #pragma unroll
            for (int mf = 0; mf < 2; ++mf)
                #pragma unroll
                for (int r = 0; r < 4; ++r)
                    acc[mf][nf][r] = fmaxf(acc[mf][nf][r] + bv, 0.f);
        }
        // ---- layer 2: coeff[e][o] = sum_j h[e][j] W2[j][o] + b2[o]
        for (int o = 0; o < P.dout; ++o) {
            float w2v[8];
            #pragma unroll
            for (int nf = 0; nf < 8; ++nf) w2v[nf] = W2s[(16 * nf + lr) * P.dout + o];
            float p[2][4];
            #pragma unroll
            for (int mf = 0; mf < 2; ++mf)
                #pragma unroll
                for (int r = 0; r < 4; ++r) {
                    float s = 0.f;
                    #pragma unroll
                    for (int nf = 0; nf < 8; ++nf) s = fmaf(acc[mf][nf][r], w2v[nf], s);
                    p[mf][r] = row_reduce16(s);   // DPP, VALU pipe
                }
            if (lr == 0) {
                float b2v = P.b2[o];
                #pragma unroll
                for (int mf = 0; mf < 2; ++mf)
                    #pragma unroll
                    for (int r = 0; r < 4; ++r)
                        Cf[wave][mf * 16 + lg * 4 + r][P.obase + o] = p[mf][r] + b2v;
            }
        }
    }
    __syncthreads();

    // ---- epilogue: combine coeffs with vectors + fused receivers-mask seg-sum
    if (l < 32) {
        const int e = e0 + l;
        if (e < NE) {
            float c[10];
            #pragma unroll
            for (int q = 0; q < 10; ++q) c[q] = Cf[wave][l][q];
            const float ax = va[(size_t)e*3+0], ay = va[(size_t)e*3+1], az = va[(size_t)e*3+2];
            const float bx = vb[(size_t)e*3+0], by = vb[(size_t)e*3+1], bz = vb[(size_t)e*3+2];
            const float cx = vc[(size_t)e*3+0], cy = vc[(size_t)e*3+1], cz = vc[(size_t)e*3+2];
            const size_t o0 = (size_t)e * 3;
            const size_t o1 = (size_t)NE * 3 + o0;
            const size_t o2 = (size_t)2 * NE * 3 + o0;
            const float f0 = c[0]*ax + c[1]*bx + c[2]*cx;
            const float f1 = c[0]*ay + c[1]*by + c[2]*cy;
            const float f2 = c[0]*az + c[1]*bz + c[2]*cz;
            const float a0 = c[3]*ax + c[4]*bx + c[5]*cx;
            const float a1 = c[3]*ay + c[4]*by + c[5]*cy;
            const float a2 = c[3]*az + c[4]*bz + c[5]*cz;
            const float d0 = c[7]*ax + c[8]*bx + c[9]*cx;
            const float d1 = c[7]*ay + c[8]*by + c[9]*cy;
            const float d2 = c[7]*az + c[8]*bz + c[9]*cz;
            out[o0+0] = f0; out[o0+1] = f1; out[o0+2] = f2;
            out[o1+0] = a0; out[o1+1] = a1; out[o1+2] = a2;
            out[o2+0] = d0; out[o2+1] = d1; out[o2+2] = d2;
            lam_ws[e] = c[6];

            // fused pass-1 seg-sum: virtual edges into global receiver nodes
            if (edge_attr[e] == -1) {
                const int rn = receivers[e];
                if (node_type[2 * rn + 1] == -1) {
                    atomicAdd(&cIn[rn], 1.0f);
                    atomicAdd(&sIn[(size_t)0 * 3 * NN + (size_t)rn * 3 + 0], f0);
                    atomicAdd(&sIn[(size_t)0 * 3 * NN + (size_t)rn * 3 + 1], f1);
                    atomicAdd(&sIn[(size_t)0 * 3 * NN + (size_t)rn * 3 + 2], f2);
                    atomicAdd(&sIn[(size_t)1 * 3 * NN + (size_t)rn * 3 + 0], a0);
                    atomicAdd(&sIn[(size_t)1 * 3 * NN + (size_t)rn * 3 + 1], a1);
                    atomicAdd(&sIn[(size_t)1 * 3 * NN + (size_t)rn * 3 + 2], a2);
                    atomicAdd(&sIn[(size_t)2 * 3 * NN + (size_t)rn * 3 + 0], d0);
                    atomicAdd(&sIn[(size_t)2 * 3 * NN + (size_t)rn * 3 + 1], d1);
                    atomicAdd(&sIn[(size_t)2 * 3 * NN + (size_t)rn * 3 + 2], d2);
                }
            }
        }
    }
}

// ---------------------------------------------------------------------------
__global__ void zero_kernel(float* __restrict__ p, int n)
{
    int i = blockIdx.x * blockDim.x + threadIdx.x;
    if (i < n) p[i] = 0.0f;
}

// fused: apply receiver-mean subtraction, then accumulate sender-mask sums
__global__ void apply_r_sum_s_kernel(const int* __restrict__ senders, const int* __restrict__ receivers,
                                     const int* __restrict__ edge_attr, const int* __restrict__ node_type,
                                     float* __restrict__ out,
                                     const float* __restrict__ sIn, const float* __restrict__ cIn,
                                     float* __restrict__ sOut, float* __restrict__ cOut)
{
    int e = blockIdx.x * blockDim.x + threadIdx.x;
    if (e >= NE) return;
    if (edge_attr[e] != -1) return;                // both masks require virtual
    const int r = receivers[e], s = senders[e];
    const bool mr = (node_type[2 * r + 1] == -1);
    const bool ms = (node_type[2 * s + 1] == -1);
    if (!mr && !ms) return;
    float v[9];
    #pragma unroll
    for (int tns = 0; tns < 3; ++tns)
        #pragma unroll
        for (int c2 = 0; c2 < 3; ++c2)
            v[tns * 3 + c2] = out[(size_t)tns * NE * 3 + (size_t)e * 3 + c2];
    if (mr) {
        const float ic = 1.0f / fmaxf(cIn[r], 1.0f);
        #pragma unroll
        for (int tns = 0; tns < 3; ++tns)
            #pragma unroll
            for (int c2 = 0; c2 < 3; ++c2) {
                v[tns * 3 + c2] -= sIn[(size_t)tns * 3 * NN + (size_t)r * 3 + c2] * ic;
                out[(size_t)tns * NE * 3 + (size_t)e * 3 + c2] = v[tns * 3 + c2];
            }
    }
    if (ms) {
        atomicAdd(&cOut[s], 1.0f);
        #pragma unroll
        for (int tns = 0; tns < 3; ++tns)
            #pragma unroll
            for (int c2 = 0; c2 < 3; ++c2)
                atomicAdd(&sOut[(size_t)tns * 3 * NN + (size_t)s * 3 + c2], v[tns * 3 + c2]);
    }
}

// pass-2 subtract (senders mask) fused with tau finalize
__global__ void apply_finalize_kernel(const int* __restrict__ senders, const int* __restrict__ receivers,
                                      const int* __restrict__ edge_attr, const int* __restrict__ node_type,
                                      const float* __restrict__ sp, const float* __restrict__ rp,
                                      const float* __restrict__ wn, const float* __restrict__ lam,
                                      const float* __restrict__ sums, const float* __restrict__ cnt,
                                      float* __restrict__ out)
{
    int e = blockIdx.x * blockDim.x + threadIdx.x;
    if (e >= NE) return;
    const int s = senders[e], r = receivers[e];
    const size_t b = (size_t)e * 3;
    const size_t tb = (size_t)NE * 3 + b;
    const size_t db = (size_t)2 * NE * 3 + b;
    float fx = out[b+0], fy = out[b+1], fz = out[b+2];
    float axx = out[tb+0], ayy = out[tb+1], azz = out[tb+2];
    const bool masked = (edge_attr[e] == -1) && (node_type[2 * s + 1] == -1);
    if (masked) {
        const float ic = 1.0f / fmaxf(cnt[s], 1.0f);
        fx -= sums[(size_t)0 * 3 * NN + (size_t)s * 3 + 0] * ic;
        fy -= sums[(size_t)0 * 3 * NN + (size_t)s * 3 + 1] * ic;
        fz -= sums[(size_t)0 * 3 * NN + (size_t)s * 3 + 2] * ic;
        axx -= sums[(size_t)1 * 3 * NN + (size_t)s * 3 + 0] * ic;
        ayy -= sums[(size_t)1 * 3 * NN + (size_t)s * 3 + 1] * ic;
        azz -= sums[(size_t)1 * 3 * NN + (size_t)s * 3 + 2] * ic;
        out[b+0] = fx; out[b+1] = fy; out[b+2] = fz;
        out[db+0] -= sums[(size_t)2 * 3 * NN + (size_t)s * 3 + 0] * ic;
        out[db+1] -= sums[(size_t)2 * 3 * NN + (size_t)s * 3 + 1] * ic;
        out[db+2] -= sums[(size_t)2 * 3 * NN + (size_t)s * 3 + 2] * ic;
    }
    const float wsv = wn[s], wrv = wn[r];
    const float inv = 1.0f / (wsv + wrv);
    const float spx = sp[b+0], spy = sp[b+1], spz = sp[b+2];
    const float rpx = rp[b+0], rpy = rp[b+1], rpz = rp[b+2];
    const float lx = rpx - (wsv * spx + wrv * rpx) * inv;
    const float ly = rpy - (wsv * spy + wrv * rpy) * inv;
    const float lz = rpz - (wsv * spz + wrv * rpz) * inv;
    const float lv = lam[e];
    const float gx = fx * lv, gy = fy * lv, gz = fz * lv;
    out[tb+0] = axx - (ly * gz - lz * gy);
    out[tb+1] = ayy - (lz * gx - lx * gz);
    out[tb+2] = azz - (lx * gy - ly * gx);
}

// ---------------------------------------------------------------------------
extern "C" void kernel_launch(void* const* d_in, const int* in_sizes, int n_in,
                              void* d_out, int out_size, void* d_ws, size_t ws_size,
                              hipStream_t stream)
{
    (void)in_sizes; (void)n_in; (void)out_size; (void)ws_size;

    const int* edge_index    = (const int*)d_in[0];
    const int* edge_attr     = (const int*)d_in[1];
    const int* node_type     = (const int*)d_in[2];
    const float* senders_pos = (const float*)d_in[3];
    const float* recv_pos    = (const float*)d_in[4];
    const float* vector_a    = (const float*)d_in[5];
    const float* vector_b    = (const float*)d_in[6];
    const float* vector_c    = (const float*)d_in[7];
    const float* latent      = (const float*)d_in[8];
    const float* w_nodes     = (const float*)d_in[9];

    MlpArgs ma;
    const int douts[4] = {3, 3, 1, 3};
    const int obase[4] = {0, 3, 6, 7};
    for (int i = 0; i < 4; ++i) {
        ma.m[i].W1 = (const float*)d_in[10 + i * 4 + 0];
        ma.m[i].b1 = (const float*)d_in[10 + i * 4 + 1];
        ma.m[i].W2 = (const float*)d_in[10 + i * 4 + 2];
        ma.m[i].b2 = (const float*)d_in[10 + i * 4 + 3];
        ma.m[i].dout = douts[i];
        ma.m[i].obase = obase[i];
    }

    float* out = (float*)d_out;
    // ws (floats): [lambda NE][sIn 9N][cIn N][sOut 9N][cOut N][w1t 32768 f-equiv]
    float* lam    = (float*)d_ws;
    float* segbuf = lam + NE;
    float* sIn    = segbuf;
    float* cIn    = sIn + 9 * NN;
    float* sOut   = cIn + NN;
    float* cOut   = sOut + 9 * NN;
    unsigned short* w1t = (unsigned short*)(cOut + NN);

    const int* senders   = edge_index;
    const int* receivers = edge_index + NE;

    hipLaunchKernelGGL(prep_w1t_kernel, dim3((4 * DD * DD + 255) / 256), dim3(256), 0, stream,
                       ma.m[0].W1, ma.m[1].W1, ma.m[2].W1, ma.m[3].W1, w1t);
    hipLaunchKernelGGL(zero_kernel, dim3((20 * NN + 255) / 256), dim3(256), 0, stream,
                       segbuf, 20 * NN);
    hipLaunchKernelGGL(mlp_mfma_kernel, dim3((NE + 127) / 128), dim3(256), 0, stream,
                       latent, w1t, vector_a, vector_b, vector_c,
                       receivers, edge_attr, node_type, out, lam, sIn, cIn, ma);
    dim3 gE((NE + 255) / 256);
    hipLaunchKernelGGL(apply_r_sum_s_kernel, gE, dim3(256), 0, stream, senders, receivers, edge_attr, node_type,
                       out, sIn, cIn, sOut, cOut);
    hipLaunchKernelGGL(apply_finalize_kernel, gE, dim3(256), 0, stream, senders, receivers, edge_attr, node_type,
                       senders_pos, recv_pos, w_nodes, lam, sOut, cOut, out);
}